// Round 2
// baseline (587.497 us; speedup 1.0000x reference)
//
#include <hip/hip_runtime.h>

typedef __bf16 bf16x8 __attribute__((ext_vector_type(8)));
typedef __bf16 bf16x4 __attribute__((ext_vector_type(4)));
typedef float  f32x4  __attribute__((ext_vector_type(4)));

// ---- workspace layout (in __bf16 elements) ----
constexpr int WS_AS0 = 0;        // A_static layer0: [64][64]
constexpr int WS_AS1 = 4096;     // A_static layer1
constexpr int WS_MT0 = 8192;     // MT0 = ph0^T@th0/sqrt(128), [256][256] bf16
constexpr int WS_MT1 = 73728;
constexpr int WS_FC0 = 139264;   // fc0 bf16 [256][256]
constexpr int WS_FC1 = 204800;   // end 270336 elems = 540672 B

static __device__ __forceinline__ f32x4 mfma16(bf16x8 a, bf16x8 b, f32x4 c) {
    return __builtin_amdgcn_mfma_f32_16x16x32_bf16(a, b, c, 0, 0, 0);
}

// ---------- prep: row-softmax of adj -> bf16 A_static ----------
__global__ void prep_adj(const float* __restrict__ adj0,
                         const float* __restrict__ adj1,
                         __bf16* __restrict__ wsb) {
    const int t = threadIdx.x;            // 128 threads: 2 layers x 64 rows
    const int l = t >> 6, r = t & 63;
    const float* a = (l ? adj1 : adj0) + r * 64;
    float mx = -3.0e38f;
    for (int c = 0; c < 64; ++c) mx = fmaxf(mx, a[c]);
    float s = 0.f;
    for (int c = 0; c < 64; ++c) s += __expf(a[c] - mx);
    const float inv = 1.f / s;
    __bf16* dst = wsb + (l ? WS_AS1 : WS_AS0) + r * 64;
    for (int c = 0; c < 64; ++c) dst[c] = (__bf16)(__expf(a[c] - mx) * inv);
}

// ---------- prep: MT[e][d] = sum_h ph[h][e]*th[h][d] / sqrt(128) ----------
__global__ void prep_M(const float* __restrict__ th0, const float* __restrict__ ph0,
                       const float* __restrict__ th1, const float* __restrict__ ph1,
                       __bf16* __restrict__ wsb) {
    const int e = blockIdx.x & 255, layer = blockIdx.x >> 8, d = threadIdx.x;
    const float* th = layer ? th1 : th0;
    const float* ph = layer ? ph1 : ph0;
    float s = 0.f;
    for (int h = 0; h < 128; ++h) s += ph[h * 256 + e] * th[h * 256 + d];
    wsb[(layer ? WS_MT1 : WS_MT0) + e * 256 + d] = (__bf16)(s * 0.088388347648318447f);
}

// ---------- prep: fc weights f32 -> bf16 ----------
__global__ void prep_w(const float* __restrict__ fc0, const float* __restrict__ fc1,
                       __bf16* __restrict__ wsb) {
    int i = blockIdx.x * 256 + threadIdx.x;
    if (i >= 131072) return;
    if (i < 65536) wsb[WS_FC0 + i] = (__bf16)fc0[i];
    else           wsb[WS_FC1 + i - 65536] = (__bf16)fc1[i - 65536];
}

// ---------- fused 2-layer GCN: one block per batch element ----------
// 512 threads = 8 waves. LDS 80384 B -> 2 blocks/CU.
__global__ __launch_bounds__(512, 4) void fused_gcn(
    const float* __restrict__ graph,
    const float* __restrict__ ln_in_g, const float* __restrict__ ln_in_b,
    const __bf16* __restrict__ wsb,
    const float* __restrict__ fcb0, const float* __restrict__ ln0_g,
    const float* __restrict__ ln0_b, const float* __restrict__ fcb1,
    float* __restrict__ outp)
{
    constexpr int XN_S = 264;   // xn / t row stride (bf16): rows shift 4 banks
    constexpr int ZT_S = 72;    // zT row stride: 144 B, 16B-aligned -> b128 reads
    constexpr int AH_S = 72;    // A_hat row stride

    __shared__ __align__(16) __bf16 sXn[64 * XN_S];   // 33792 B  (R0: xn)
    __shared__ __align__(16) __bf16 sR1[256 * ZT_S];  // 36864 B  (R1: t[64][256]@XN_S, then zT[256][72])
    __shared__ __align__(16) __bf16 sAh[64 * AH_S];   //  9216 B
    __shared__ float sRed[128];                       //   512 B

    const int tid = threadIdx.x;
    const int w = tid >> 6, lane = tid & 63;
    const int l15 = lane & 15, qd = lane >> 4;
    const int b = blockIdx.x;

    // ---- P1: LayerNorm(graph[b]) -> sXn (bf16). 8 threads per row.
    {
        if (tid < 128) sRed[tid] = 0.f;
        const int r = tid >> 3, ci = (tid & 7) * 32;
        const float* gp = graph + (size_t)b * 16384 + r * 256 + ci;
        f32x4 v[8];
        float s = 0.f, s2 = 0.f;
        #pragma unroll
        for (int j = 0; j < 8; ++j) {
            v[j] = *(const f32x4*)(gp + j * 4);
            #pragma unroll
            for (int e = 0; e < 4; ++e) { s += v[j][e]; s2 += v[j][e] * v[j][e]; }
        }
        #pragma unroll
        for (int m = 1; m <= 4; m <<= 1) { s += __shfl_xor(s, m); s2 += __shfl_xor(s2, m); }
        const float mean = s * (1.f / 256.f);
        const float var  = s2 * (1.f / 256.f) - mean * mean;
        const float rstd = rsqrtf(var + 1e-5f);
        #pragma unroll
        for (int j = 0; j < 8; ++j) {
            f32x4 gg = *(const f32x4*)(ln_in_g + ci + j * 4);
            f32x4 bb = *(const f32x4*)(ln_in_b + ci + j * 4);
            bf16x4 pk;
            #pragma unroll
            for (int e = 0; e < 4; ++e)
                pk[e] = (__bf16)((v[j][e] - mean) * rstd * gg[e] + bb[e]);
            *(bf16x4*)&sXn[r * XN_S + ci + j * 4] = pk;
        }
    }
    __syncthreads();

    #pragma unroll
    for (int layer = 0; layer < 2; ++layer) {
        const __bf16* As  = wsb + (layer ? WS_AS1 : WS_AS0);
        const __bf16* mtw = wsb + (layer ? WS_MT1 : WS_MT0);
        const __bf16* fcw = wsb + (layer ? WS_FC1 : WS_FC0);
        const float*  fcb = layer ? fcb1 : fcb0;

        // ---- PT: t = xn @ M, computed transposed so C-frags pack into
        //          row-major t[node][d] with 8B writes. A=MT rows, B=xn rows.
        {
            bf16x8 amt[16];
            #pragma unroll
            for (int jm = 0; jm < 2; ++jm)
                #pragma unroll
                for (int kk = 0; kk < 8; ++kk)
                    amt[jm * 8 + kk] = *(const bf16x8*)(mtw + ((w * 2 + jm) * 16 + l15) * 256 + kk * 32 + qd * 8);
            f32x4 tacc[2][4];
            #pragma unroll
            for (int jm = 0; jm < 2; ++jm)
                #pragma unroll
                for (int nt = 0; nt < 4; ++nt) tacc[jm][nt] = (f32x4){0.f, 0.f, 0.f, 0.f};
            #pragma unroll
            for (int nt = 0; nt < 4; ++nt)
                #pragma unroll
                for (int kk = 0; kk < 8; ++kk) {
                    bf16x8 bx = *(const bf16x8*)&sXn[(nt * 16 + l15) * XN_S + kk * 32 + qd * 8];
                    tacc[0][nt] = mfma16(amt[kk], bx, tacc[0][nt]);
                    tacc[1][nt] = mfma16(amt[8 + kk], bx, tacc[1][nt]);
                }
            #pragma unroll
            for (int jm = 0; jm < 2; ++jm)
                #pragma unroll
                for (int nt = 0; nt < 4; ++nt) {
                    bf16x4 pk;
                    #pragma unroll
                    for (int r = 0; r < 4; ++r) pk[r] = (__bf16)tacc[jm][nt][r];
                    // lane holds 4 consecutive d = (w*2+jm)*16 + qd*4 + r at node nt*16+l15
                    *(bf16x4*)&sR1[(nt * 16 + l15) * XN_S + (w * 2 + jm) * 16 + qd * 4] = pk;
                }
        }
        __syncthreads();

        // ---- Phase2: waves 0-3: scores = t@xn^T -> softmax -> +A_static -> sAh
        //              waves 4-7: z = xn@fc^T into registers (packed bf16)
        bf16x4 zpk[16];
        if (w < 4) {
            const int mb = w * 16;
            bf16x8 at[8];
            #pragma unroll
            for (int kk = 0; kk < 8; ++kk)
                at[kk] = *(const bf16x8*)&sR1[(mb + l15) * XN_S + kk * 32 + qd * 8];
            f32x4 sc[4];
            #pragma unroll
            for (int nt = 0; nt < 4; ++nt) sc[nt] = (f32x4){0.f, 0.f, 0.f, 0.f};
            #pragma unroll
            for (int nt = 0; nt < 4; ++nt)
                #pragma unroll
                for (int kk = 0; kk < 8; ++kk) {
                    bf16x8 bx = *(const bf16x8*)&sXn[(nt * 16 + l15) * XN_S + kk * 32 + qd * 8];
                    sc[nt] = mfma16(at[kk], bx, sc[nt]);
                }
            // softmax over 64 cols (4 nt regs x 16 lanes); scale folded into MT
            #pragma unroll
            for (int r = 0; r < 4; ++r) {
                float v[4];
                #pragma unroll
                for (int nt = 0; nt < 4; ++nt) v[nt] = sc[nt][r];
                float mx = fmaxf(fmaxf(v[0], v[1]), fmaxf(v[2], v[3]));
                #pragma unroll
                for (int m = 1; m <= 8; m <<= 1) mx = fmaxf(mx, __shfl_xor(mx, m));
                float e[4], sum = 0.f;
                #pragma unroll
                for (int nt = 0; nt < 4; ++nt) { e[nt] = __expf(v[nt] - mx); sum += e[nt]; }
                #pragma unroll
                for (int m = 1; m <= 8; m <<= 1) sum += __shfl_xor(sum, m);
                const float inv = 1.f / sum;
                const int row = mb + qd * 4 + r;
                #pragma unroll
                for (int nt = 0; nt < 4; ++nt) {
                    const int col = nt * 16 + l15;
                    sAh[row * AH_S + col] = (__bf16)(e[nt] * inv + (float)As[row * 64 + col]);
                }
            }
        } else {
            const int mt = w - 4;            // this wave's node m-tile
            bf16x8 ax[8];
            #pragma unroll
            for (int kk = 0; kk < 8; ++kk)
                ax[kk] = *(const bf16x8*)&sXn[(mt * 16 + l15) * XN_S + kk * 32 + qd * 8];
            #pragma unroll
            for (int ot = 0; ot < 16; ++ot) {
                bf16x8 bfc[8];
                #pragma unroll
                for (int kk = 0; kk < 8; ++kk)
                    bfc[kk] = *(const bf16x8*)(fcw + (ot * 16 + l15) * 256 + kk * 32 + qd * 8);
                f32x4 a0 = {0.f, 0.f, 0.f, 0.f}, a1 = {0.f, 0.f, 0.f, 0.f};
                #pragma unroll
                for (int kk = 0; kk < 4; ++kk) {
                    a0 = mfma16(ax[kk], bfc[kk], a0);
                    a1 = mfma16(ax[4 + kk], bfc[4 + kk], a1);
                }
                #pragma unroll
                for (int r = 0; r < 4; ++r) zpk[ot][r] = (__bf16)(a0[r] + a1[r]);
            }
        }
        __syncthreads();

        // ---- Phase3: waves 4-7 write zT[o][node] (t region now dead)
        if (w >= 4) {
            const int mt = w - 4;
            #pragma unroll
            for (int ot = 0; ot < 16; ++ot)
                *(bf16x4*)&sR1[(ot * 16 + l15) * ZT_S + mt * 16 + qd * 4] = zpk[ot];
        }
        __syncthreads();

        // ---- P5: out = A_hat @ zT + fcb; fused LN+leaky (layer0) or store.
        {
            const int mb = (w & 3) * 16, ng = w >> 2;
            bf16x8 aa[2];
            #pragma unroll
            for (int kk = 0; kk < 2; ++kk)
                aa[kk] = *(const bf16x8*)&sAh[(mb + l15) * AH_S + kk * 32 + qd * 8];
            f32x4 oacc[8];
            #pragma unroll
            for (int j = 0; j < 8; ++j) {
                const int o = ng * 128 + j * 16 + l15;
                f32x4 acc = {0.f, 0.f, 0.f, 0.f};
                #pragma unroll
                for (int kk = 0; kk < 2; ++kk) {
                    bf16x8 bb = *(const bf16x8*)&sR1[o * ZT_S + kk * 32 + qd * 8];
                    acc = mfma16(aa[kk], bb, acc);
                }
                const float bias = fcb[o];
                #pragma unroll
                for (int r = 0; r < 4; ++r) acc[r] += bias;
                oacc[j] = acc;
            }

            if (layer == 0) {
                #pragma unroll
                for (int r = 0; r < 4; ++r) {
                    float s = 0.f, s2 = 0.f;
                    #pragma unroll
                    for (int j = 0; j < 8; ++j) { const float vv = oacc[j][r]; s += vv; s2 += vv * vv; }
                    #pragma unroll
                    for (int m = 1; m <= 8; m <<= 1) { s += __shfl_xor(s, m); s2 += __shfl_xor(s2, m); }
                    if (l15 == 0) {
                        const int row = mb + qd * 4 + r;
                        atomicAdd(&sRed[row], s);
                        atomicAdd(&sRed[64 + row], s2);
                    }
                }
                __syncthreads();
                float mean4[4], rstd4[4];
                #pragma unroll
                for (int r = 0; r < 4; ++r) {
                    const int row = mb + qd * 4 + r;
                    const float mean = sRed[row] * (1.f / 256.f);
                    const float var  = sRed[64 + row] * (1.f / 256.f) - mean * mean;
                    mean4[r] = mean;
                    rstd4[r] = rsqrtf(var + 1e-5f);
                }
                #pragma unroll
                for (int j = 0; j < 8; ++j) {
                    const int o = ng * 128 + j * 16 + l15;
                    const float g = ln0_g[o], bb = ln0_b[o];
                    #pragma unroll
                    for (int r = 0; r < 4; ++r) {
                        float y = (oacc[j][r] - mean4[r]) * rstd4[r] * g + bb;
                        y = (y >= 0.f) ? y : 0.1f * y;   // LeakyReLU(0.1)
                        sXn[(mb + qd * 4 + r) * XN_S + o] = (__bf16)y;
                    }
                }
                __syncthreads();
            } else {
                float* op = outp + (size_t)b * 16384;
                #pragma unroll
                for (int j = 0; j < 8; ++j) {
                    const int o = ng * 128 + j * 16 + l15;
                    #pragma unroll
                    for (int r = 0; r < 4; ++r)
                        op[(mb + qd * 4 + r) * 256 + o] = oacc[j][r];
                }
            }
        }
    }
}

extern "C" void kernel_launch(void* const* d_in, const int* in_sizes, int n_in,
                              void* d_out, int out_size, void* d_ws, size_t ws_size,
                              hipStream_t stream) {
    const float* graph   = (const float*)d_in[0];
    const float* ln_in_g = (const float*)d_in[1];
    const float* ln_in_b = (const float*)d_in[2];
    const float* adj0    = (const float*)d_in[3];
    const float* th0     = (const float*)d_in[4];
    const float* ph0     = (const float*)d_in[5];
    const float* fcw0    = (const float*)d_in[6];
    const float* fcb0    = (const float*)d_in[7];
    const float* ln0_g   = (const float*)d_in[8];
    const float* ln0_b   = (const float*)d_in[9];
    const float* adj1    = (const float*)d_in[10];
    const float* th1     = (const float*)d_in[11];
    const float* ph1     = (const float*)d_in[12];
    const float* fcw1    = (const float*)d_in[13];
    const float* fcb1    = (const float*)d_in[14];
    __bf16* wsb = (__bf16*)d_ws;

    prep_adj<<<1, 128, 0, stream>>>(adj0, adj1, wsb);
    prep_M<<<512, 256, 0, stream>>>(th0, ph0, th1, ph1, wsb);
    prep_w<<<512, 256, 0, stream>>>(fcw0, fcw1, wsb);
    fused_gcn<<<2048, 512, 0, stream>>>(graph, ln_in_g, ln_in_b, wsb,
                                        fcb0, ln0_g, ln0_b, fcb1, (float*)d_out);
}

// Round 3
// 439.643 us; speedup vs baseline: 1.3363x; 1.3363x over previous
//
#include <hip/hip_runtime.h>

typedef __bf16 bf16x8 __attribute__((ext_vector_type(8)));
typedef __bf16 bf16x4 __attribute__((ext_vector_type(4)));
typedef float  f32x4  __attribute__((ext_vector_type(4)));

// ---- workspace layout (in __bf16 elements) ----
constexpr int WS_AS0 = 0;        // A_static layer0: [64][64]
constexpr int WS_AS1 = 4096;     // A_static layer1
constexpr int WS_MT0 = 8192;     // MT0 = ph0^T@th0/sqrt(128), [256][256] bf16
constexpr int WS_MT1 = 73728;
constexpr int WS_FC0 = 139264;   // fc0 bf16 [256][256]
constexpr int WS_FC1 = 204800;   // end 270336 elems = 540672 B

static __device__ __forceinline__ f32x4 mfma16(bf16x8 a, bf16x8 b, f32x4 c) {
    return __builtin_amdgcn_mfma_f32_16x16x32_bf16(a, b, c, 0, 0, 0);
}

// ---------- prep: row-softmax of adj -> bf16 A_static ----------
__global__ void prep_adj(const float* __restrict__ adj0,
                         const float* __restrict__ adj1,
                         __bf16* __restrict__ wsb) {
    const int t = threadIdx.x;            // 128 threads: 2 layers x 64 rows
    const int l = t >> 6, r = t & 63;
    const float* a = (l ? adj1 : adj0) + r * 64;
    float mx = -3.0e38f;
    for (int c = 0; c < 64; ++c) mx = fmaxf(mx, a[c]);
    float s = 0.f;
    for (int c = 0; c < 64; ++c) s += __expf(a[c] - mx);
    const float inv = 1.f / s;
    __bf16* dst = wsb + (l ? WS_AS1 : WS_AS0) + r * 64;
    for (int c = 0; c < 64; ++c) dst[c] = (__bf16)(__expf(a[c] - mx) * inv);
}

// ---------- prep: MT[e][d] = sum_h ph[h][e]*th[h][d] / sqrt(128) ----------
__global__ void prep_M(const float* __restrict__ th0, const float* __restrict__ ph0,
                       const float* __restrict__ th1, const float* __restrict__ ph1,
                       __bf16* __restrict__ wsb) {
    const int e = blockIdx.x & 255, layer = blockIdx.x >> 8, d = threadIdx.x;
    const float* th = layer ? th1 : th0;
    const float* ph = layer ? ph1 : ph0;
    float s = 0.f;
    for (int h = 0; h < 128; ++h) s += ph[h * 256 + e] * th[h * 256 + d];
    wsb[(layer ? WS_MT1 : WS_MT0) + e * 256 + d] = (__bf16)(s * 0.088388347648318447f);
}

// ---------- prep: fc weights f32 -> bf16 ----------
__global__ void prep_w(const float* __restrict__ fc0, const float* __restrict__ fc1,
                       __bf16* __restrict__ wsb) {
    int i = blockIdx.x * 256 + threadIdx.x;
    if (i >= 131072) return;
    if (i < 65536) wsb[WS_FC0 + i] = (__bf16)fc0[i];
    else           wsb[WS_FC1 + i - 65536] = (__bf16)fc1[i - 65536];
}

// ---------- fused 2-layer GCN: one block per batch element ----------
// 512 threads = 8 waves. LDS 80384 B -> 2 blocks/CU.
__global__ __launch_bounds__(512, 4) void fused_gcn(
    const float* __restrict__ graph,
    const float* __restrict__ ln_in_g, const float* __restrict__ ln_in_b,
    const __bf16* __restrict__ wsb,
    const float* __restrict__ fcb0, const float* __restrict__ ln0_g,
    const float* __restrict__ ln0_b, const float* __restrict__ fcb1,
    float* __restrict__ outp)
{
    constexpr int XN_S = 264;   // xn / t row stride (bf16)
    constexpr int ZT_S = 72;    // zT row stride: 144 B, 16B-aligned -> b128 reads
    constexpr int AH_S = 72;    // A_hat row stride

    __shared__ __align__(16) __bf16 sXn[64 * XN_S];   // 33792 B  (xn, persistent per layer)
    __shared__ __align__(16) __bf16 sR1[256 * ZT_S];  // 36864 B  (t[64][.]@XN_S, then zT[256][72])
    __shared__ __align__(16) __bf16 sAh[64 * AH_S];   //  9216 B
    __shared__ float sRed[128];                       //   512 B

    const int tid = threadIdx.x;
    const int w = tid >> 6, lane = tid & 63;
    const int l15 = lane & 15, qd = lane >> 4;
    const int b = blockIdx.x;

    // ---- P1: LayerNorm(graph[b]) -> sXn (bf16). 8 threads per row.
    {
        if (tid < 128) sRed[tid] = 0.f;
        const int r = tid >> 3, ci = (tid & 7) * 32;
        const float* gp = graph + (size_t)b * 16384 + r * 256 + ci;
        f32x4 v[8];
        float s = 0.f, s2 = 0.f;
        #pragma unroll
        for (int j = 0; j < 8; ++j) {
            v[j] = *(const f32x4*)(gp + j * 4);
            #pragma unroll
            for (int e = 0; e < 4; ++e) { s += v[j][e]; s2 += v[j][e] * v[j][e]; }
        }
        #pragma unroll
        for (int m = 1; m <= 4; m <<= 1) { s += __shfl_xor(s, m); s2 += __shfl_xor(s2, m); }
        const float mean = s * (1.f / 256.f);
        const float var  = s2 * (1.f / 256.f) - mean * mean;
        const float rstd = rsqrtf(var + 1e-5f);
        #pragma unroll
        for (int j = 0; j < 8; ++j) {
            f32x4 gg = *(const f32x4*)(ln_in_g + ci + j * 4);
            f32x4 bb = *(const f32x4*)(ln_in_b + ci + j * 4);
            bf16x4 pk;
            #pragma unroll
            for (int e = 0; e < 4; ++e)
                pk[e] = (__bf16)((v[j][e] - mean) * rstd * gg[e] + bb[e]);
            *(bf16x4*)&sXn[r * XN_S + ci + j * 4] = pk;
        }
    }
    __syncthreads();

    #pragma unroll
    for (int layer = 0; layer < 2; ++layer) {
        const __bf16* As  = wsb + (layer ? WS_AS1 : WS_AS0);
        const __bf16* mtw = wsb + (layer ? WS_MT1 : WS_MT0);
        const __bf16* fcw = wsb + (layer ? WS_FC1 : WS_FC0);
        const float*  fcb = layer ? fcb1 : fcb0;

        // ---- PT: t = xn @ M, row-major t via packed C-frag writes.
        //      kk-outer: only 8 accs + 2 transient A-frags live (no spill).
        {
            f32x4 tacc[2][4];
            #pragma unroll
            for (int jm = 0; jm < 2; ++jm)
                #pragma unroll
                for (int nt = 0; nt < 4; ++nt) tacc[jm][nt] = (f32x4){0.f, 0.f, 0.f, 0.f};
            #pragma unroll
            for (int kk = 0; kk < 8; ++kk) {
                bf16x8 a0 = *(const bf16x8*)(mtw + ((w * 2 + 0) * 16 + l15) * 256 + kk * 32 + qd * 8);
                bf16x8 a1 = *(const bf16x8*)(mtw + ((w * 2 + 1) * 16 + l15) * 256 + kk * 32 + qd * 8);
                #pragma unroll
                for (int nt = 0; nt < 4; ++nt) {
                    bf16x8 bx = *(const bf16x8*)&sXn[(nt * 16 + l15) * XN_S + kk * 32 + qd * 8];
                    tacc[0][nt] = mfma16(a0, bx, tacc[0][nt]);
                    tacc[1][nt] = mfma16(a1, bx, tacc[1][nt]);
                }
            }
            #pragma unroll
            for (int jm = 0; jm < 2; ++jm)
                #pragma unroll
                for (int nt = 0; nt < 4; ++nt) {
                    bf16x4 pk;
                    #pragma unroll
                    for (int r = 0; r < 4; ++r) pk[r] = (__bf16)tacc[jm][nt][r];
                    // lane holds 4 consecutive d = (w*2+jm)*16+qd*4+r at node nt*16+l15
                    *(bf16x4*)&sR1[(nt * 16 + l15) * XN_S + (w * 2 + jm) * 16 + qd * 4] = pk;
                }
        }
        __syncthreads();

        // ---- P3 (waves 0-3): scores = t@xn^T (K=256) -> softmax -> +As -> sAh
        //      P4-hi (waves 4-7): z for o in [128,256) into zpk regs (fc read once)
        bf16x4 zpk[8];
        if (w < 4) {
            const int mb = w * 16;
            bf16x8 at[8];
            #pragma unroll
            for (int kk = 0; kk < 8; ++kk)
                at[kk] = *(const bf16x8*)&sR1[(mb + l15) * XN_S + kk * 32 + qd * 8];
            f32x4 sc[4];
            #pragma unroll
            for (int nt = 0; nt < 4; ++nt) sc[nt] = (f32x4){0.f, 0.f, 0.f, 0.f};
            #pragma unroll
            for (int nt = 0; nt < 4; ++nt)
                #pragma unroll
                for (int kk = 0; kk < 8; ++kk) {
                    bf16x8 bx = *(const bf16x8*)&sXn[(nt * 16 + l15) * XN_S + kk * 32 + qd * 8];
                    sc[nt] = mfma16(at[kk], bx, sc[nt]);
                }
            #pragma unroll
            for (int r = 0; r < 4; ++r) {
                float v[4];
                #pragma unroll
                for (int nt = 0; nt < 4; ++nt) v[nt] = sc[nt][r];
                float mx = fmaxf(fmaxf(v[0], v[1]), fmaxf(v[2], v[3]));
                #pragma unroll
                for (int m = 1; m <= 8; m <<= 1) mx = fmaxf(mx, __shfl_xor(mx, m));
                float e[4], sum = 0.f;
                #pragma unroll
                for (int nt = 0; nt < 4; ++nt) { e[nt] = __expf(v[nt] - mx); sum += e[nt]; }
                #pragma unroll
                for (int m = 1; m <= 8; m <<= 1) sum += __shfl_xor(sum, m);
                const float inv = 1.f / sum;
                const int row = mb + qd * 4 + r;
                #pragma unroll
                for (int nt = 0; nt < 4; ++nt) {
                    const int col = nt * 16 + l15;
                    sAh[row * AH_S + col] = (__bf16)(e[nt] * inv + (float)As[row * 64 + col]);
                }
            }
        } else {
            const int ob = 128 + (w - 4) * 32;
            #pragma unroll
            for (int jm = 0; jm < 2; ++jm) {
                bf16x8 bfc[8];
                #pragma unroll
                for (int kk = 0; kk < 8; ++kk)
                    bfc[kk] = *(const bf16x8*)(fcw + (ob + jm * 16 + l15) * 256 + kk * 32 + qd * 8);
                #pragma unroll
                for (int m = 0; m < 4; ++m) {
                    f32x4 az = {0.f, 0.f, 0.f, 0.f};
                    #pragma unroll
                    for (int kk = 0; kk < 8; ++kk) {
                        bf16x8 ax = *(const bf16x8*)&sXn[(m * 16 + l15) * XN_S + kk * 32 + qd * 8];
                        az = mfma16(ax, bfc[kk], az);
                    }
                    bf16x4 pk;
                    #pragma unroll
                    for (int r = 0; r < 4; ++r) pk[r] = (__bf16)az[r];
                    zpk[jm * 4 + m] = pk;
                }
            }
        }
        __syncthreads();   // t dead; zT region free

        // ---- P4-lo (all 8 waves): z for o in [0,128) straight to zT;
        //      waves 4-7 also flush zpk (o in [128,256)).
        {
            if (w >= 4) {
                const int ob = 128 + (w - 4) * 32;
                #pragma unroll
                for (int jm = 0; jm < 2; ++jm)
                    #pragma unroll
                    for (int m = 0; m < 4; ++m)
                        *(bf16x4*)&sR1[(ob + jm * 16 + l15) * ZT_S + m * 16 + qd * 4] = zpk[jm * 4 + m];
            }
            const int o = w * 16 + l15;       // covers 0..127
            bf16x8 bfc[8];
            #pragma unroll
            for (int kk = 0; kk < 8; ++kk)
                bfc[kk] = *(const bf16x8*)(fcw + o * 256 + kk * 32 + qd * 8);
            #pragma unroll
            for (int m = 0; m < 4; ++m) {
                f32x4 az = {0.f, 0.f, 0.f, 0.f};
                #pragma unroll
                for (int kk = 0; kk < 8; ++kk) {
                    bf16x8 ax = *(const bf16x8*)&sXn[(m * 16 + l15) * XN_S + kk * 32 + qd * 8];
                    az = mfma16(ax, bfc[kk], az);
                }
                bf16x4 pk;
                #pragma unroll
                for (int r = 0; r < 4; ++r) pk[r] = (__bf16)az[r];
                *(bf16x4*)&sR1[o * ZT_S + m * 16 + qd * 4] = pk;
            }
        }
        __syncthreads();

        // ---- P5: out = A_hat @ zT + fcb; fused LN+leaky (layer0) or store.
        {
            const int mb = (w & 3) * 16, ng = w >> 2;
            bf16x8 aa[2];
            #pragma unroll
            for (int kk = 0; kk < 2; ++kk)
                aa[kk] = *(const bf16x8*)&sAh[(mb + l15) * AH_S + kk * 32 + qd * 8];
            f32x4 oacc[8];
            #pragma unroll
            for (int j = 0; j < 8; ++j) {
                const int o = ng * 128 + j * 16 + l15;
                f32x4 acc = {0.f, 0.f, 0.f, 0.f};
                #pragma unroll
                for (int kk = 0; kk < 2; ++kk) {
                    bf16x8 bb = *(const bf16x8*)&sR1[o * ZT_S + kk * 32 + qd * 8];
                    acc = mfma16(aa[kk], bb, acc);
                }
                const float bias = fcb[o];
                #pragma unroll
                for (int r = 0; r < 4; ++r) acc[r] += bias;
                oacc[j] = acc;
            }

            if (layer == 0) {
                #pragma unroll
                for (int r = 0; r < 4; ++r) {
                    float s = 0.f, s2 = 0.f;
                    #pragma unroll
                    for (int j = 0; j < 8; ++j) { const float vv = oacc[j][r]; s += vv; s2 += vv * vv; }
                    #pragma unroll
                    for (int m = 1; m <= 8; m <<= 1) { s += __shfl_xor(s, m); s2 += __shfl_xor(s2, m); }
                    if (l15 == 0) {
                        const int row = mb + qd * 4 + r;
                        atomicAdd(&sRed[row], s);
                        atomicAdd(&sRed[64 + row], s2);
                    }
                }
                __syncthreads();
                float mean4[4], rstd4[4];
                #pragma unroll
                for (int r = 0; r < 4; ++r) {
                    const int row = mb + qd * 4 + r;
                    const float mean = sRed[row] * (1.f / 256.f);
                    const float var  = sRed[64 + row] * (1.f / 256.f) - mean * mean;
                    mean4[r] = mean;
                    rstd4[r] = rsqrtf(var + 1e-5f);
                }
                #pragma unroll
                for (int j = 0; j < 8; ++j) {
                    const int o = ng * 128 + j * 16 + l15;
                    const float g = ln0_g[o], bb = ln0_b[o];
                    #pragma unroll
                    for (int r = 0; r < 4; ++r) {
                        float y = (oacc[j][r] - mean4[r]) * rstd4[r] * g + bb;
                        y = (y >= 0.f) ? y : 0.1f * y;   // LeakyReLU(0.1)
                        sXn[(mb + qd * 4 + r) * XN_S + o] = (__bf16)y;
                    }
                }
                __syncthreads();
            } else {
                float* op = outp + (size_t)b * 16384;
                #pragma unroll
                for (int j = 0; j < 8; ++j) {
                    const int o = ng * 128 + j * 16 + l15;
                    #pragma unroll
                    for (int r = 0; r < 4; ++r)
                        op[(mb + qd * 4 + r) * 256 + o] = oacc[j][r];
                }
            }
        }
    }
}

extern "C" void kernel_launch(void* const* d_in, const int* in_sizes, int n_in,
                              void* d_out, int out_size, void* d_ws, size_t ws_size,
                              hipStream_t stream) {
    const float* graph   = (const float*)d_in[0];
    const float* ln_in_g = (const float*)d_in[1];
    const float* ln_in_b = (const float*)d_in[2];
    const float* adj0    = (const float*)d_in[3];
    const float* th0     = (const float*)d_in[4];
    const float* ph0     = (const float*)d_in[5];
    const float* fcw0    = (const float*)d_in[6];
    const float* fcb0    = (const float*)d_in[7];
    const float* ln0_g   = (const float*)d_in[8];
    const float* ln0_b   = (const float*)d_in[9];
    const float* adj1    = (const float*)d_in[10];
    const float* th1     = (const float*)d_in[11];
    const float* ph1     = (const float*)d_in[12];
    const float* fcw1    = (const float*)d_in[13];
    const float* fcb1    = (const float*)d_in[14];
    __bf16* wsb = (__bf16*)d_ws;

    prep_adj<<<1, 128, 0, stream>>>(adj0, adj1, wsb);
    prep_M<<<512, 256, 0, stream>>>(th0, ph0, th1, ph1, wsb);
    prep_w<<<512, 256, 0, stream>>>(fcw0, fcw1, wsb);
    fused_gcn<<<2048, 512, 0, stream>>>(graph, ln_in_g, ln_in_b, wsb,
                                        fcb0, ln0_g, ln0_b, fcb1, (float*)d_out);
}

// Round 4
// 405.540 us; speedup vs baseline: 1.4487x; 1.0841x over previous
//
#include <hip/hip_runtime.h>

typedef __bf16 bf16x8 __attribute__((ext_vector_type(8)));
typedef __bf16 bf16x4 __attribute__((ext_vector_type(4)));
typedef float  f32x4  __attribute__((ext_vector_type(4)));

// ---- workspace layout (in __bf16 elements) ----
constexpr int WS_AS0 = 0;        // A_static layer0: [64][64]
constexpr int WS_AS1 = 4096;     // A_static layer1
constexpr int WS_MT0 = 8192;     // MT0 = ph0^T@th0/sqrt(128), [256][256] bf16
constexpr int WS_MT1 = 73728;
constexpr int WS_FC0 = 139264;   // fc0 bf16 [256][256]
constexpr int WS_FC1 = 204800;   // end 270336 elems = 540672 B

static __device__ __forceinline__ f32x4 mfma16(bf16x8 a, bf16x8 b, f32x4 c) {
    return __builtin_amdgcn_mfma_f32_16x16x32_bf16(a, b, c, 0, 0, 0);
}

// ---------- single prep kernel: adj softmax | MT gemm | fc cast ----------
// grid: [0,32) adj rows (1 wave/row) | [32,544) MT (block=e,layer) | [544,800) fc
__global__ void prep_all(const float* __restrict__ adj0, const float* __restrict__ adj1,
                         const float* __restrict__ th0,  const float* __restrict__ ph0,
                         const float* __restrict__ th1,  const float* __restrict__ ph1,
                         const float* __restrict__ fc0,  const float* __restrict__ fc1,
                         __bf16* __restrict__ wsb) {
    const int blk = blockIdx.x, tid = threadIdx.x;
    if (blk < 32) {
        const int w = tid >> 6, lane = tid & 63;
        const int row = blk * 4 + w;              // 0..127
        const int layer = row >> 6, r = row & 63;
        const float* a = (layer ? adj1 : adj0) + r * 64;
        const float v = a[lane];
        float mx = v;
        #pragma unroll
        for (int m = 1; m < 64; m <<= 1) mx = fmaxf(mx, __shfl_xor(mx, m));
        float e = __expf(v - mx), sum = e;
        #pragma unroll
        for (int m = 1; m < 64; m <<= 1) sum += __shfl_xor(sum, m);
        wsb[(layer ? WS_AS1 : WS_AS0) + r * 64 + lane] = (__bf16)(e / sum);
    } else if (blk < 544) {
        const int e = (blk - 32) & 255, layer = (blk - 32) >> 8, d = tid;
        const float* th = layer ? th1 : th0;
        const float* ph = layer ? ph1 : ph0;
        float s = 0.f;
        #pragma unroll 8
        for (int h = 0; h < 128; ++h) s += ph[h * 256 + e] * th[h * 256 + d];
        wsb[(layer ? WS_MT1 : WS_MT0) + e * 256 + d] = (__bf16)(s * 0.088388347648318447f);
    } else {
        const int i = (blk - 544) * 512 + tid * 2;    // 0..131070 step 2
        if (i < 65536) {
            wsb[WS_FC0 + i]     = (__bf16)fc0[i];
            wsb[WS_FC0 + i + 1] = (__bf16)fc0[i + 1];
        } else {
            wsb[WS_FC1 + i - 65536] = (__bf16)fc1[i - 65536];
            wsb[WS_FC1 + i - 65535] = (__bf16)fc1[i - 65535];
        }
    }
}

// ---------- fused 2-layer GCN: one block per batch element ----------
// 512 threads = 8 waves. LDS 80384 B -> 2 blocks/CU.
// Phase discipline: NO register state crosses any __syncthreads().
__global__ __launch_bounds__(512, 4) void fused_gcn(
    const float* __restrict__ graph,
    const float* __restrict__ ln_in_g, const float* __restrict__ ln_in_b,
    const __bf16* __restrict__ wsb,
    const float* __restrict__ fcb0, const float* __restrict__ ln0_g,
    const float* __restrict__ ln0_b, const float* __restrict__ fcb1,
    float* __restrict__ outp)
{
    constexpr int XN_S = 264;   // xn / t row stride (bf16)
    constexpr int ZT_S = 72;    // zT row stride: 144 B, 16B-aligned -> b128 reads
    constexpr int AH_S = 72;    // A_hat row stride

    __shared__ __align__(16) __bf16 sXn[64 * XN_S];   // 33792 B  (xn, persistent per layer)
    __shared__ __align__(16) __bf16 sR1[256 * ZT_S];  // 36864 B  (t[64][.]@XN_S, then zT[256][72])
    __shared__ __align__(16) __bf16 sAh[64 * AH_S];   //  9216 B  (As staged, then A_hat)
    __shared__ float sRed[128];                       //   512 B

    const int tid = threadIdx.x;
    const int w = tid >> 6, lane = tid & 63;
    const int l15 = lane & 15, qd = lane >> 4;
    const int b = blockIdx.x;

    // ---- P1: LayerNorm(graph[b]) -> sXn (bf16). 8 threads per row.
    {
        if (tid < 128) sRed[tid] = 0.f;
        const int r = tid >> 3, ci = (tid & 7) * 32;
        const float* gp = graph + (size_t)b * 16384 + r * 256 + ci;
        f32x4 v[8];
        float s = 0.f, s2 = 0.f;
        #pragma unroll
        for (int j = 0; j < 8; ++j) {
            v[j] = *(const f32x4*)(gp + j * 4);
            #pragma unroll
            for (int e = 0; e < 4; ++e) { s += v[j][e]; s2 += v[j][e] * v[j][e]; }
        }
        #pragma unroll
        for (int m = 1; m <= 4; m <<= 1) { s += __shfl_xor(s, m); s2 += __shfl_xor(s2, m); }
        const float mean = s * (1.f / 256.f);
        const float var  = s2 * (1.f / 256.f) - mean * mean;
        const float rstd = rsqrtf(var + 1e-5f);
        #pragma unroll
        for (int j = 0; j < 8; ++j) {
            f32x4 gg = *(const f32x4*)(ln_in_g + ci + j * 4);
            f32x4 bb = *(const f32x4*)(ln_in_b + ci + j * 4);
            bf16x4 pk;
            #pragma unroll
            for (int e = 0; e < 4; ++e)
                pk[e] = (__bf16)((v[j][e] - mean) * rstd * gg[e] + bb[e]);
            *(bf16x4*)&sXn[r * XN_S + ci + j * 4] = pk;
        }
    }
    __syncthreads();

    #pragma unroll 1
    for (int layer = 0; layer < 2; ++layer) {
        const __bf16* As  = wsb + (layer ? WS_AS1 : WS_AS0);
        const __bf16* mtw = wsb + (layer ? WS_MT1 : WS_MT0);
        const __bf16* fcw = wsb + (layer ? WS_FC1 : WS_FC0);
        const float*  fcb = layer ? fcb1 : fcb0;

        // ---- PT: t = xn @ M (row-major t via packed C-frag writes), jm-outer
        //      so the 8 global A-frag loads pipeline. Also stage As -> sAh.
        {
            {   // stage A_static into sAh (one b128 per thread)
                const int r = tid >> 3, c8 = (tid & 7) * 8;
                *(bf16x8*)&sAh[r * AH_S + c8] = *(const bf16x8*)(As + r * 64 + c8);
            }
            #pragma unroll
            for (int jm = 0; jm < 2; ++jm) {
                bf16x8 amt[8];
                #pragma unroll
                for (int kk = 0; kk < 8; ++kk)
                    amt[kk] = *(const bf16x8*)(mtw + ((w * 2 + jm) * 16 + l15) * 256 + kk * 32 + qd * 8);
                f32x4 tacc[4];
                #pragma unroll
                for (int nt = 0; nt < 4; ++nt) tacc[nt] = (f32x4){0.f, 0.f, 0.f, 0.f};
                #pragma unroll
                for (int kk = 0; kk < 8; ++kk)
                    #pragma unroll
                    for (int nt = 0; nt < 4; ++nt) {
                        bf16x8 bx = *(const bf16x8*)&sXn[(nt * 16 + l15) * XN_S + kk * 32 + qd * 8];
                        tacc[nt] = mfma16(amt[kk], bx, tacc[nt]);
                    }
                #pragma unroll
                for (int nt = 0; nt < 4; ++nt) {
                    bf16x4 pk;
                    #pragma unroll
                    for (int r = 0; r < 4; ++r) pk[r] = (__bf16)tacc[nt][r];
                    // lane holds 4 consecutive d=(w*2+jm)*16+qd*4+r at node nt*16+l15
                    *(bf16x4*)&sR1[(nt * 16 + l15) * XN_S + (w * 2 + jm) * 16 + qd * 4] = pk;
                }
            }
        }
        __syncthreads();

        // ---- P3 (waves 0-3): scores = t@xn^T (K=256) -> softmax -> +As (from LDS)
        if (w < 4) {
            const int mb = w * 16;
            bf16x8 at[8];
            #pragma unroll
            for (int kk = 0; kk < 8; ++kk)
                at[kk] = *(const bf16x8*)&sR1[(mb + l15) * XN_S + kk * 32 + qd * 8];
            f32x4 sc[4];
            #pragma unroll
            for (int nt = 0; nt < 4; ++nt) sc[nt] = (f32x4){0.f, 0.f, 0.f, 0.f};
            #pragma unroll
            for (int nt = 0; nt < 4; ++nt)
                #pragma unroll
                for (int kk = 0; kk < 8; ++kk) {
                    bf16x8 bx = *(const bf16x8*)&sXn[(nt * 16 + l15) * XN_S + kk * 32 + qd * 8];
                    sc[nt] = mfma16(at[kk], bx, sc[nt]);
                }
            #pragma unroll
            for (int r = 0; r < 4; ++r) {
                float v[4];
                #pragma unroll
                for (int nt = 0; nt < 4; ++nt) v[nt] = sc[nt][r];
                float mx = fmaxf(fmaxf(v[0], v[1]), fmaxf(v[2], v[3]));
                #pragma unroll
                for (int m = 1; m <= 8; m <<= 1) mx = fmaxf(mx, __shfl_xor(mx, m));
                float e[4], sum = 0.f;
                #pragma unroll
                for (int nt = 0; nt < 4; ++nt) { e[nt] = __expf(v[nt] - mx); sum += e[nt]; }
                #pragma unroll
                for (int m = 1; m <= 8; m <<= 1) sum += __shfl_xor(sum, m);
                const float inv = 1.f / sum;
                const int row = mb + qd * 4 + r;
                #pragma unroll
                for (int nt = 0; nt < 4; ++nt) {
                    const int col = nt * 16 + l15;
                    const float as = (float)sAh[row * AH_S + col];   // staged As
                    sAh[row * AH_S + col] = (__bf16)(e[nt] * inv + as);
                }
            }
        }
        __syncthreads();   // t dead; zT region free

        // ---- PZ (all 8 waves): z = xn@fc^T, o-block of 32 per wave,
        //      written straight to zT. No registers survive past the barrier.
        {
            #pragma unroll
            for (int jm = 0; jm < 2; ++jm) {
                const int o = w * 32 + jm * 16 + l15;
                bf16x8 bfc[8];
                #pragma unroll
                for (int kk = 0; kk < 8; ++kk)
                    bfc[kk] = *(const bf16x8*)(fcw + o * 256 + kk * 32 + qd * 8);
                f32x4 zacc[4];
                #pragma unroll
                for (int m = 0; m < 4; ++m) zacc[m] = (f32x4){0.f, 0.f, 0.f, 0.f};
                #pragma unroll
                for (int kk = 0; kk < 8; ++kk)
                    #pragma unroll
                    for (int m = 0; m < 4; ++m) {
                        bf16x8 ax = *(const bf16x8*)&sXn[(m * 16 + l15) * XN_S + kk * 32 + qd * 8];
                        zacc[m] = mfma16(ax, bfc[kk], zacc[m]);
                    }
                #pragma unroll
                for (int m = 0; m < 4; ++m) {
                    bf16x4 pk;
                    #pragma unroll
                    for (int r = 0; r < 4; ++r) pk[r] = (__bf16)zacc[m][r];
                    *(bf16x4*)&sR1[o * ZT_S + m * 16 + qd * 4] = pk;
                }
            }
        }
        __syncthreads();

        // ---- P5: out = A_hat @ zT + fcb; fused LN+leaky (layer0) or store.
        {
            const int mb = (w & 3) * 16, ng = w >> 2;
            bf16x8 aa[2];
            #pragma unroll
            for (int kk = 0; kk < 2; ++kk)
                aa[kk] = *(const bf16x8*)&sAh[(mb + l15) * AH_S + kk * 32 + qd * 8];
            f32x4 oacc[8];
            #pragma unroll
            for (int j = 0; j < 8; ++j) {
                const int o = ng * 128 + j * 16 + l15;
                f32x4 acc = {0.f, 0.f, 0.f, 0.f};
                #pragma unroll
                for (int kk = 0; kk < 2; ++kk) {
                    bf16x8 bb = *(const bf16x8*)&sR1[o * ZT_S + kk * 32 + qd * 8];
                    acc = mfma16(aa[kk], bb, acc);
                }
                const float bias = fcb[o];
                #pragma unroll
                for (int r = 0; r < 4; ++r) acc[r] += bias;
                oacc[j] = acc;
            }

            if (layer == 0) {
                #pragma unroll
                for (int r = 0; r < 4; ++r) {
                    float s = 0.f, s2 = 0.f;
                    #pragma unroll
                    for (int j = 0; j < 8; ++j) { const float vv = oacc[j][r]; s += vv; s2 += vv * vv; }
                    #pragma unroll
                    for (int m = 1; m <= 8; m <<= 1) { s += __shfl_xor(s, m); s2 += __shfl_xor(s2, m); }
                    if (l15 == 0) {
                        const int row = mb + qd * 4 + r;
                        atomicAdd(&sRed[row], s);
                        atomicAdd(&sRed[64 + row], s2);
                    }
                }
                __syncthreads();
                float mean4[4], rstd4[4];
                #pragma unroll
                for (int r = 0; r < 4; ++r) {
                    const int row = mb + qd * 4 + r;
                    const float mean = sRed[row] * (1.f / 256.f);
                    const float var  = sRed[64 + row] * (1.f / 256.f) - mean * mean;
                    mean4[r] = mean;
                    rstd4[r] = rsqrtf(var + 1e-5f);
                }
                #pragma unroll
                for (int j = 0; j < 8; ++j) {
                    const int o = ng * 128 + j * 16 + l15;
                    const float g = ln0_g[o], bb = ln0_b[o];
                    #pragma unroll
                    for (int r = 0; r < 4; ++r) {
                        float y = (oacc[j][r] - mean4[r]) * rstd4[r] * g + bb;
                        y = (y >= 0.f) ? y : 0.1f * y;   // LeakyReLU(0.1)
                        sXn[(mb + qd * 4 + r) * XN_S + o] = (__bf16)y;
                    }
                }
                __syncthreads();
            } else {
                float* op = outp + (size_t)b * 16384;
                #pragma unroll
                for (int j = 0; j < 8; ++j) {
                    const int o = ng * 128 + j * 16 + l15;
                    #pragma unroll
                    for (int r = 0; r < 4; ++r)
                        op[(mb + qd * 4 + r) * 256 + o] = oacc[j][r];
                }
            }
        }
    }
}

extern "C" void kernel_launch(void* const* d_in, const int* in_sizes, int n_in,
                              void* d_out, int out_size, void* d_ws, size_t ws_size,
                              hipStream_t stream) {
    const float* graph   = (const float*)d_in[0];
    const float* ln_in_g = (const float*)d_in[1];
    const float* ln_in_b = (const float*)d_in[2];
    const float* adj0    = (const float*)d_in[3];
    const float* th0     = (const float*)d_in[4];
    const float* ph0     = (const float*)d_in[5];
    const float* fcw0    = (const float*)d_in[6];
    const float* fcb0    = (const float*)d_in[7];
    const float* ln0_g   = (const float*)d_in[8];
    const float* ln0_b   = (const float*)d_in[9];
    const float* adj1    = (const float*)d_in[10];
    const float* th1     = (const float*)d_in[11];
    const float* ph1     = (const float*)d_in[12];
    const float* fcw1    = (const float*)d_in[13];
    const float* fcb1    = (const float*)d_in[14];
    __bf16* wsb = (__bf16*)d_ws;

    prep_all<<<800, 256, 0, stream>>>(adj0, adj1, th0, ph0, th1, ph1, fcw0, fcw1, wsb);
    fused_gcn<<<2048, 512, 0, stream>>>(graph, ln_in_g, ln_in_b, wsb,
                                        fcb0, ln0_g, ln0_b, fcb1, (float*)d_out);
}